// Round 1
// baseline (219.195 us; speedup 1.0000x reference)
//
#include <hip/hip_runtime.h>
#include <stdint.h>

// SpecAugment: out = x * mask, x:(64,1,4000,128) f32.
// Mask from jax.random.key(1) -> split 4 -> uniform draws (threefry2x32,
// partitionable path). Band params precomputed into ws by a tiny kernel.

#define RATE 0.5f
#define POLICY 3
#define FREQ_MASK 15
#define TIME_MASK 35
#define B 64
#define T 4000
#define F 128

__device__ __forceinline__ uint32_t rotl32(uint32_t x, int r) {
  return (x << r) | (x >> (32 - r));
}

// Standard Threefry-2x32, 20 rounds (JAX's threefry2x32_p).
__device__ __forceinline__ void threefry2x32(uint32_t k0, uint32_t k1,
                                             uint32_t x0, uint32_t x1,
                                             uint32_t* o0, uint32_t* o1) {
  const uint32_t ks2 = k0 ^ k1 ^ 0x1BD11BDAu;
  x0 += k0; x1 += k1;
  // rounds 1-4 (rot set A)
  x0 += x1; x1 = rotl32(x1, 13); x1 ^= x0;
  x0 += x1; x1 = rotl32(x1, 15); x1 ^= x0;
  x0 += x1; x1 = rotl32(x1, 26); x1 ^= x0;
  x0 += x1; x1 = rotl32(x1,  6); x1 ^= x0;
  x0 += k1; x1 += ks2 + 1u;
  // rounds 5-8 (rot set B)
  x0 += x1; x1 = rotl32(x1, 17); x1 ^= x0;
  x0 += x1; x1 = rotl32(x1, 29); x1 ^= x0;
  x0 += x1; x1 = rotl32(x1, 16); x1 ^= x0;
  x0 += x1; x1 = rotl32(x1, 24); x1 ^= x0;
  x0 += ks2; x1 += k0 + 2u;
  // rounds 9-12 (A)
  x0 += x1; x1 = rotl32(x1, 13); x1 ^= x0;
  x0 += x1; x1 = rotl32(x1, 15); x1 ^= x0;
  x0 += x1; x1 = rotl32(x1, 26); x1 ^= x0;
  x0 += x1; x1 = rotl32(x1,  6); x1 ^= x0;
  x0 += k0; x1 += k1 + 3u;
  // rounds 13-16 (B)
  x0 += x1; x1 = rotl32(x1, 17); x1 ^= x0;
  x0 += x1; x1 = rotl32(x1, 29); x1 ^= x0;
  x0 += x1; x1 = rotl32(x1, 16); x1 ^= x0;
  x0 += x1; x1 = rotl32(x1, 24); x1 ^= x0;
  x0 += k1; x1 += ks2 + 4u;
  // rounds 17-20 (A)
  x0 += x1; x1 = rotl32(x1, 13); x1 ^= x0;
  x0 += x1; x1 = rotl32(x1, 15); x1 ^= x0;
  x0 += x1; x1 = rotl32(x1, 26); x1 ^= x0;
  x0 += x1; x1 = rotl32(x1,  6); x1 ^= x0;
  x0 += ks2; x1 += k0 + 5u;
  *o0 = x0; *o1 = x1;
}

__device__ __forceinline__ float bits_to_uniform(uint32_t bits) {
  uint32_t fb = (bits >> 9) | 0x3f800000u;
  float f = __uint_as_float(fb) - 1.0f;
  return fmaxf(f, 0.0f);
}

// One thread per (batch, policy) pair: i = b*3+p in [0,192).
// Partitionable threefry path:
//   split(key,4): key_i = (o0,o1) of enc(key, (0,i))
//   uniform bits[i] = o0 ^ o1 of enc(subkey, (0,i))
__global__ void band_kernel(int2* __restrict__ tband, int2* __restrict__ fband) {
  const int i = threadIdx.x;
  if (i >= B * POLICY) return;
  const uint32_t K0 = 0u, K1 = 1u;  // jax.random.key(1)
  uint32_t a0, a1, b0, b1, c0, c1, d0, d1;
  threefry2x32(K0, K1, 0u, 0u, &a0, &a1);  // kt_apply key
  threefry2x32(K0, K1, 0u, 1u, &b0, &b1);  // kt_start key
  threefry2x32(K0, K1, 0u, 2u, &c0, &c1);  // kf_apply key
  threefry2x32(K0, K1, 0u, 3u, &d0, &d1);  // kf_start key

  uint32_t o0, o1;
  threefry2x32(a0, a1, 0u, (uint32_t)i, &o0, &o1);
  const float u_ta = bits_to_uniform(o0 ^ o1);
  threefry2x32(b0, b1, 0u, (uint32_t)i, &o0, &o1);
  const float u_ts = bits_to_uniform(o0 ^ o1);
  threefry2x32(c0, c1, 0u, (uint32_t)i, &o0, &o1);
  const float u_fa = bits_to_uniform(o0 ^ o1);
  threefry2x32(d0, d1, 0u, (uint32_t)i, &o0, &o1);
  const float u_fs = bits_to_uniform(o0 ^ o1);

  const bool ap_t = u_ta < RATE;
  const bool ap_f = u_fa < RATE;
  const int st = (int)floorf(u_ts * (float)(T - TIME_MASK));  // *3965
  const int sf = (int)floorf(u_fs * (float)(F - FREQ_MASK));  // *113
  tband[i] = ap_t ? make_int2(st, st + TIME_MASK) : make_int2(0, 0);
  fband[i] = ap_f ? make_int2(sf, sf + FREQ_MASK) : make_int2(0, 0);
}

// grid = (500, 64), block = 256. Each thread: one float4 (4 freq bins).
// i in [0,128000): t = i>>5, f4 = i&31.
__global__ __launch_bounds__(256) void apply_kernel(
    const float4* __restrict__ x, float4* __restrict__ out,
    const int2* __restrict__ tband, const int2* __restrict__ fband) {
  const int b = blockIdx.y;
  const int i = blockIdx.x * 256 + threadIdx.x;
  const int t = i >> 5;
  const int f0 = (i & 31) << 2;

  const int2 tb0 = tband[b * 3 + 0];
  const int2 tb1 = tband[b * 3 + 1];
  const int2 tb2 = tband[b * 3 + 2];
  const bool keep_t = !((t >= tb0.x && t < tb0.y) ||
                        (t >= tb1.x && t < tb1.y) ||
                        (t >= tb2.x && t < tb2.y));
  const int2 fb0 = fband[b * 3 + 0];
  const int2 fb1 = fband[b * 3 + 1];
  const int2 fb2 = fband[b * 3 + 2];

  const long idx = (long)b * (T * F / 4) + i;
  float4 v = x[idx];
  float r[4];
  const float* vp = (const float*)&v;
#pragma unroll
  for (int j = 0; j < 4; ++j) {
    const int f = f0 + j;
    const bool keep_f = !((f >= fb0.x && f < fb0.y) ||
                          (f >= fb1.x && f < fb1.y) ||
                          (f >= fb2.x && f < fb2.y));
    r[j] = (keep_t && keep_f) ? vp[j] : 0.0f;
  }
  out[idx] = *(const float4*)r;
}

extern "C" void kernel_launch(void* const* d_in, const int* in_sizes, int n_in,
                              void* d_out, int out_size, void* d_ws, size_t ws_size,
                              hipStream_t stream) {
  const float4* x = (const float4*)d_in[0];
  float4* out = (float4*)d_out;
  int2* tband = (int2*)d_ws;                       // 192 * 8 B
  int2* fband = (int2*)((char*)d_ws + B * POLICY * sizeof(int2));

  band_kernel<<<1, 192, 0, stream>>>(tband, fband);

  dim3 grid(T * F / 4 / 256, B);  // (500, 64)
  apply_kernel<<<grid, 256, 0, stream>>>(x, out, tband, fband);
}

// Round 3
// 213.904 us; speedup vs baseline: 1.0247x; 1.0247x over previous
//
#include <hip/hip_runtime.h>
#include <stdint.h>

// SpecAugment: out = x * mask, x:(64,1,4000,128) f32.
// Mask params from jax.random.key(1) (threefry2x32, partitionable path),
// computed in-kernel by 12 threads per block into LDS (fused, no band kernel).

#define RATE 0.5f
#define POLICY 3
#define FREQ_MASK 15
#define TIME_MASK 35
#define B 64
#define T 4000
#define F 128
#define PER_BATCH (T * F / 4)   // 128000 float4
#define BLK_CHUNK 1024          // float4 per block
#define ITERS 4                 // BLK_CHUNK / 256

typedef float f32x4 __attribute__((ext_vector_type(4)));  // clang vector: OK for nontemporal builtins

__device__ __forceinline__ uint32_t rotl32(uint32_t x, int r) {
  return (x << r) | (x >> (32 - r));
}

// Standard Threefry-2x32, 20 rounds (JAX's threefry2x32_p). Verified exact R1.
__device__ __forceinline__ void threefry2x32(uint32_t k0, uint32_t k1,
                                             uint32_t x0, uint32_t x1,
                                             uint32_t* o0, uint32_t* o1) {
  const uint32_t ks2 = k0 ^ k1 ^ 0x1BD11BDAu;
  x0 += k0; x1 += k1;
  x0 += x1; x1 = rotl32(x1, 13); x1 ^= x0;
  x0 += x1; x1 = rotl32(x1, 15); x1 ^= x0;
  x0 += x1; x1 = rotl32(x1, 26); x1 ^= x0;
  x0 += x1; x1 = rotl32(x1,  6); x1 ^= x0;
  x0 += k1; x1 += ks2 + 1u;
  x0 += x1; x1 = rotl32(x1, 17); x1 ^= x0;
  x0 += x1; x1 = rotl32(x1, 29); x1 ^= x0;
  x0 += x1; x1 = rotl32(x1, 16); x1 ^= x0;
  x0 += x1; x1 = rotl32(x1, 24); x1 ^= x0;
  x0 += ks2; x1 += k0 + 2u;
  x0 += x1; x1 = rotl32(x1, 13); x1 ^= x0;
  x0 += x1; x1 = rotl32(x1, 15); x1 ^= x0;
  x0 += x1; x1 = rotl32(x1, 26); x1 ^= x0;
  x0 += x1; x1 = rotl32(x1,  6); x1 ^= x0;
  x0 += k0; x1 += k1 + 3u;
  x0 += x1; x1 = rotl32(x1, 17); x1 ^= x0;
  x0 += x1; x1 = rotl32(x1, 29); x1 ^= x0;
  x0 += x1; x1 = rotl32(x1, 16); x1 ^= x0;
  x0 += x1; x1 = rotl32(x1, 24); x1 ^= x0;
  x0 += k1; x1 += ks2 + 4u;
  x0 += x1; x1 = rotl32(x1, 13); x1 ^= x0;
  x0 += x1; x1 = rotl32(x1, 15); x1 ^= x0;
  x0 += x1; x1 = rotl32(x1, 26); x1 ^= x0;
  x0 += x1; x1 = rotl32(x1,  6); x1 ^= x0;
  x0 += ks2; x1 += k0 + 5u;
  *o0 = x0; *o1 = x1;
}

__device__ __forceinline__ float bits_to_uniform(uint32_t bits) {
  uint32_t fb = (bits >> 9) | 0x3f800000u;
  float f = __uint_as_float(fb) - 1.0f;
  return fmaxf(f, 0.0f);
}

// grid = (125, 64), block = 256. Each thread: 4 float4 (block chunk 16 KB).
// Threads 0..11 compute the 12 uniform draws for batch b into LDS.
//   us[d*3 + p]: d = draw kind (0=t_apply,1=t_start,2=f_apply,3=f_start)
__global__ __launch_bounds__(256) void specaug_kernel(
    const f32x4* __restrict__ x, f32x4* __restrict__ out) {
  __shared__ float us[12];
  const int b = blockIdx.y;
  const int tid = threadIdx.x;

  // ---- issue all 4 streaming loads first (in flight during PRNG) ----
  const size_t base = (size_t)b * PER_BATCH + (size_t)blockIdx.x * BLK_CHUNK + tid;
  f32x4 v0 = __builtin_nontemporal_load(&x[base + 0 * 256]);
  f32x4 v1 = __builtin_nontemporal_load(&x[base + 1 * 256]);
  f32x4 v2 = __builtin_nontemporal_load(&x[base + 2 * 256]);
  f32x4 v3 = __builtin_nontemporal_load(&x[base + 3 * 256]);

  // ---- 12 threads: subkey d = enc(key1,(0,d)); draw = enc(subkey,(0,b*3+p)) ----
  if (tid < 12) {
    const int d = tid / 3;          // draw kind
    const int p = tid - d * 3;      // policy
    uint32_t k0, k1, o0, o1;
    threefry2x32(0u, 1u, 0u, (uint32_t)d, &k0, &k1);
    threefry2x32(k0, k1, 0u, (uint32_t)(b * 3 + p), &o0, &o1);
    us[tid] = bits_to_uniform(o0 ^ o1);
  }
  __syncthreads();

  // ---- band boundaries (empty band encoded as start==length) ----
  int tlo[3], flo[3];
#pragma unroll
  for (int p = 0; p < 3; ++p) {
    const bool at = us[0 * 3 + p] < RATE;
    const bool af = us[2 * 3 + p] < RATE;
    const int ts = (int)floorf(us[1 * 3 + p] * (float)(T - TIME_MASK));
    const int fs = (int)floorf(us[3 * 3 + p] * (float)(F - FREQ_MASK));
    tlo[p] = at ? ts : T;
    flo[p] = af ? fs : F;
  }

  // Within-batch float4 index j = blockIdx.x*1024 + iter*256 + tid.
  // f0 = (j&31)<<2 depends only on tid; t = blockIdx.x*32 + iter*8 + (tid>>5).
  const int f0 = (tid & 31) << 2;
  bool kf[4];
#pragma unroll
  for (int j = 0; j < 4; ++j) {
    const int f = f0 + j;
    kf[j] = !((f >= flo[0] && f < flo[0] + FREQ_MASK) ||
              (f >= flo[1] && f < flo[1] + FREQ_MASK) ||
              (f >= flo[2] && f < flo[2] + FREQ_MASK));
  }
  const int t_base = blockIdx.x * 32 + (tid >> 5);

  f32x4 vv[4] = {v0, v1, v2, v3};
#pragma unroll
  for (int i = 0; i < ITERS; ++i) {
    const int t = t_base + i * 8;
    const bool kt = !((t >= tlo[0] && t < tlo[0] + TIME_MASK) ||
                      (t >= tlo[1] && t < tlo[1] + TIME_MASK) ||
                      (t >= tlo[2] && t < tlo[2] + TIME_MASK));
    f32x4 r;
    r.x = (kt && kf[0]) ? vv[i].x : 0.0f;
    r.y = (kt && kf[1]) ? vv[i].y : 0.0f;
    r.z = (kt && kf[2]) ? vv[i].z : 0.0f;
    r.w = (kt && kf[3]) ? vv[i].w : 0.0f;
    __builtin_nontemporal_store(r, &out[base + i * 256]);
  }
}

extern "C" void kernel_launch(void* const* d_in, const int* in_sizes, int n_in,
                              void* d_out, int out_size, void* d_ws, size_t ws_size,
                              hipStream_t stream) {
  const f32x4* x = (const f32x4*)d_in[0];
  f32x4* out = (f32x4*)d_out;
  dim3 grid(PER_BATCH / BLK_CHUNK, B);  // (125, 64)
  specaug_kernel<<<grid, 256, 0, stream>>>(x, out);
}